// Round 7
// baseline (51.402 us; speedup 1.0000x reference)
//
#include <hip/hip_runtime.h>

#define BB 64
#define SS 2048
#define DD 128
#define DDV 256

// tanh(x) = 1 - 2/(e^{2x}+1) with raw v_rcp_f32 (no IEEE refine).
// |rel err| ~1e-7 vs 7.1e-3 output threshold (validated rounds 4-6).
__device__ __forceinline__ float fast_tanh(float x) {
    const float t = __expf(2.0f * x);
    return 1.0f - 2.0f * __builtin_amdgcn_rcpf(t + 1.0f);
}

// ---------------- Kernel 1: blend[b*S+s] = 0.5*scores1 ----------------
// (+0.5 shift dropped: cancels in softmax #1. 0.5 scale folded into w4.)
// 4 waves/block, 8 rows/wave -> 32 rows/block, 4096 blocks. Lanes 0-31 take
// the q half, 32-63 the k half; one float4 per lane per row. At the HBM
// floor (~20 us for 128 MiB).
__global__ __launch_bounds__(256) void k_blend(const float* __restrict__ q,
                                               const float* __restrict__ k,
                                               const float* __restrict__ wv,
                                               float* __restrict__ blend) {
    const int wave = threadIdx.x >> 6;
    const int lane = threadIdx.x & 63;
    const float* src = (lane < 32) ? q : k;
    float4 w4 = *(const float4*)(wv + lane * 4);
    w4.x *= 0.5f; w4.y *= 0.5f; w4.z *= 0.5f; w4.w *= 0.5f;
    const int row0 = blockIdx.x * 32 + wave * 8;
    const float* base = src + (size_t)row0 * DD + (lane & 31) * 4;
#pragma unroll
    for (int i = 0; i < 8; ++i) {
        const float4 x = *(const float4*)(base + (size_t)i * DD);
        float acc = fast_tanh(x.x) * w4.x + fast_tanh(x.y) * w4.y
                  + fast_tanh(x.z) * w4.z + fast_tanh(x.w) * w4.w;
#pragma unroll
        for (int o = 32; o; o >>= 1) acc += __shfl_xor(acc, o, 64);
        if (lane == 0) blend[row0 + i] = acc;
    }
}

// ---------------- Kernel 2: per-batch stats + weights(LDS) + PV -> out -------
// One 1024-thread block per batch. Phase A: double-softmax stats via wave
// butterflies + 16-entry LDS combine (4 barriers), weights written to LDS.
// Phase B: wave w accumulates rows {w, w+16, ...} (16 consecutive rows in
// flight across the block), lane owns a float4 column slice, unroll 8.
// Phase C: fixed-order cross-wave reduce -> out. Fully deterministic.
__global__ __launch_bounds__(1024) void k_batch(const float* __restrict__ blend,
                                                const int* __restrict__ valid,
                                                const float* __restrict__ values,
                                                float* __restrict__ out) {
    __shared__ float  wlds[SS];        // 8 KB attention weights
    __shared__ float4 sacc[16][64];    // 16 KB cross-wave PV reduce
    __shared__ float  r0[16], r1[16], r2[16], r3[16];
    const int b = blockIdx.x;
    const int t = threadIdx.x;
    const int w = t >> 6, lane = t & 63;
    const float* rowp = blend + (size_t)b * SS;

    // ---- Phase A: stats ----
    const float v0 = rowp[t];
    const float v1 = rowp[t + 1024];

    float m = fmaxf(v0, v1);
#pragma unroll
    for (int o = 32; o; o >>= 1) m = fmaxf(m, __shfl_xor(m, o, 64));
    if (lane == 0) r0[w] = m;
    __syncthreads();
    float m1 = r0[0];
#pragma unroll
    for (int i = 1; i < 16; ++i) m1 = fmaxf(m1, r0[i]);

    const float e0 = expf(v0 - m1), e1 = expf(v1 - m1);
    float s = e0 + e1;
#pragma unroll
    for (int o = 32; o; o >>= 1) s += __shfl_xor(s, o, 64);
    if (lane == 0) r1[w] = s;
    __syncthreads();
    float Z1 = 0.f;
#pragma unroll
    for (int i = 0; i < 16; ++i) Z1 += r1[i];
    const float invZ1 = 1.f / Z1;
    const float p0 = e0 * invZ1, p1 = e1 * invZ1;

    const int L = valid[b];

    float mm = -1e30f;                  // L >= 1 so index 0 always valid
    if (t < L)        mm = p0;
    if (t + 1024 < L) mm = fmaxf(mm, p1);
#pragma unroll
    for (int o = 32; o; o >>= 1) mm = fmaxf(mm, __shfl_xor(mm, o, 64));
    if (lane == 0) r2[w] = mm;
    __syncthreads();
    float m2 = r2[0];
#pragma unroll
    for (int i = 1; i < 16; ++i) m2 = fmaxf(m2, r2[i]);

    const float f0 = (t < L)        ? expf(p0 - m2) : 0.f;
    const float f1 = (t + 1024 < L) ? expf(p1 - m2) : 0.f;
    float s2 = f0 + f1;
#pragma unroll
    for (int o = 32; o; o >>= 1) s2 += __shfl_xor(s2, o, 64);
    if (lane == 0) r3[w] = s2;
    __syncthreads();
    float Z2 = 0.f;
#pragma unroll
    for (int i = 0; i < 16; ++i) Z2 += r3[i];
    const float invZ2 = 1.f / Z2;

    wlds[t]        = f0 * invZ2;       // exact 0 for s >= L
    wlds[t + 1024] = f1 * invZ2;
    __syncthreads();

    // ---- Phase B: PV ----
    const int niter = (L > w) ? ((L - w + 15) >> 4) : 0;
    const float* vb = values + ((size_t)b * SS + w) * DDV + lane * 4;
    float4 acc = {0.f, 0.f, 0.f, 0.f};
#pragma unroll 8
    for (int i = 0; i < niter; ++i) {
        const float wt = wlds[w + 16 * i];
        const float4 v4 = *(const float4*)(vb + (size_t)i * 16 * DDV);
        acc.x += wt * v4.x;
        acc.y += wt * v4.y;
        acc.z += wt * v4.z;
        acc.w += wt * v4.w;
    }
    sacc[w][lane] = acc;
    __syncthreads();

    // ---- Phase C: fixed-order cross-wave reduce -> out ----
    if (t < 64) {
        float4 r = {0.f, 0.f, 0.f, 0.f};
#pragma unroll
        for (int ww = 0; ww < 16; ++ww) {
            const float4 a = sacc[ww][t];
            r.x += a.x; r.y += a.y; r.z += a.z; r.w += a.w;
        }
        *(float4*)(out + (size_t)b * DDV + t * 4) = r;
    }
}

extern "C" void kernel_launch(void* const* d_in, const int* in_sizes, int n_in,
                              void* d_out, int out_size, void* d_ws, size_t ws_size,
                              hipStream_t stream) {
    const float* q    = (const float*)d_in[0];
    const float* k    = (const float*)d_in[1];
    const float* v    = (const float*)d_in[2];
    const int*   vlen = (const int*)d_in[3];
    const float* wv   = (const float*)d_in[4];
    // d_in[5..7] (w2, w_v2_w, w_v2_b) are dead: softmax over singleton axis == 1.

    float* blend = (float*)d_ws;                  // B*S floats (512 KB)
    float* out   = (float*)d_out;

    k_blend<<<dim3(BB * SS / 32), dim3(256),  0, stream>>>(q, k, wv, blend);
    k_batch<<<dim3(BB),           dim3(1024), 0, stream>>>(blend, vlen, v, out);
}